// Round 8
// baseline (63.727 us; speedup 1.0000x reference)
//
#include <hip/hip_runtime.h>
#include <math.h>

#define NDET 16
#define NDIM 16

// ---- quad (4-lane) DPP helpers: pure VALU, no LDS path (R2-verbatim) -----
template<int OWNER>
__device__ __forceinline__ float bcast4f(float v) {
    constexpr int ctrl = OWNER * 0x55;  // quad_perm:[OWNER]*4
    return __int_as_float(
        __builtin_amdgcn_mov_dpp(__float_as_int(v), ctrl, 0xF, 0xF, true));
}
template<int OWNER>
__device__ __forceinline__ int bcast4i(int v) {
    constexpr int ctrl = OWNER * 0x55;
    return __builtin_amdgcn_mov_dpp(v, ctrl, 0xF, 0xF, true);
}

// ---- pivoted LU step (column K), 16x16 over a 4-lane quad ----------------
// lane l owns columns 4l..4l+3 as c[j][row]; all indices compile-time.
// Arithmetic identical to the R2-passing kernel; only instruction forms cut:
//  * key pack fused: (bits & 0x7FFFFFF0) | i   (== (bits(|v|) & ~15) | i)
//  * elimination staged: batch independent DPP broadcasts, then FMAs.
template<int K>
__device__ __forceinline__ void lu_step(float (&c)[4][16], float &prod, int &nswap) {
    constexpr int OWNER = K >> 2;   // lane owning column K
    constexpr int KC    = K & 3;    // its local column index

    if constexpr (K < 15) {
        // linear packed argmax over rows K..15 (fused pack: 2 ops/element)
        unsigned key = (__float_as_uint(c[KC][K]) & 0x7FFFFFF0u) | (unsigned)K;
        #pragma unroll
        for (int i = K + 1; i < 16; ++i) {
            const unsigned ki = (__float_as_uint(c[KC][i]) & 0x7FFFFFF0u) | (unsigned)i;
            key = key > ki ? key : ki;
        }
        const int pidx = bcast4i<OWNER>((int)(key & 15u));
        nswap += (pidx != K) ? 1 : 0;

        // row swap K <-> pidx (cndmask chain; no-op when pidx==K)
        #pragma unroll
        for (int i = K + 1; i < 16; ++i) {
            const bool msel = (i == pidx);
            #pragma unroll
            for (int j = 0; j < 4; ++j) {
                const float tk = c[j][K], ti = c[j][i];
                c[j][K] = msel ? ti : tk;
                c[j][i] = msel ? tk : ti;
            }
        }
    }

    const float pivot = bcast4f<OWNER>(c[KC][K]);
    prod *= pivot;

    if constexpr (K < 15) {
        const float rp = __builtin_amdgcn_rcpf(pivot);

        // stage 1: independent DPP broadcasts (no inter-DPP dependencies)
        float bm[16];   // const-indexed -> registers
        #pragma unroll
        for (int i = K + 1; i < 16; ++i)
            bm[i] = bcast4f<OWNER>(c[KC][i]);

        // stage 2: multipliers + rank-1 update (issue-rich, independent rows)
        #pragma unroll
        for (int i = K + 1; i < 16; ++i) {
            const float mik = bm[i] * rp;
            #pragma unroll
            for (int j = 0; j < 4; ++j)
                c[j][i] = fmaf(-mik, c[j][K], c[j][i]);
        }
    }
}

template<int K>
__device__ __forceinline__ void lu_all(float (&c)[4][16], float &prod, int &nswap) {
    lu_step<K>(c, prod, nswap);
    if constexpr (K < 15) lu_all<K + 1>(c, prod, nswap);
}

// 128 threads = 2 waves = 32 quads = 2 samples per workgroup.
__global__ __launch_bounds__(128) void logabssumdet_kernel(
    const float* __restrict__ a,
    const float* __restrict__ b,
    const float* __restrict__ w,
    float* __restrict__ out,
    int n_samples)
{
    const int tid    = threadIdx.x;
    const int lane4  = tid & 3;
    const int group  = tid >> 2;                    // 0..31 in block
    const int mat_id = blockIdx.x * 32 + group;     // = sample*16 + det
    const int n_mats = n_samples * NDET;

    __shared__ float sx[32];
    __shared__ float ss[32];

    float x = 0.0f, sgn = 1.0f;

    if (mat_id < n_mats) {
        #pragma unroll 1   // one LU body in I-cache (R2 structure: fastest)
        for (int m = 0; m < 2; ++m) {
            const float* src = (m == 0) ? a : b;
            const float4* mb =
                reinterpret_cast<const float4*>(src + (size_t)mat_id * (NDIM * NDIM)) + lane4;

            float c[4][16];
            #pragma unroll
            for (int i = 0; i < 16; ++i) {
                const float4 v = mb[i * 4];         // 64B contiguous per quad
                c[0][i] = v.x; c[1][i] = v.y; c[2][i] = v.z; c[3][i] = v.w;
            }

            float prod = 1.0f;
            int nswap = 0;
            lu_all<0>(c, prod, nswap);

            x += __logf(fabsf(prod));
            sgn = (prod < 0.0f) ? -sgn : sgn;
            sgn = (nswap & 1)   ? -sgn : sgn;
        }
    }

    if (lane4 == 0) { sx[group] = x; ss[group] = sgn; }
    __syncthreads();

    // 2 samples per block; one thread finishes each sample's 16-det LSE
    if (tid < 2) {
        const int sample = blockIdx.x * 2 + tid;
        if (sample < n_samples) {
            const int base = tid * NDET;
            float xmax = -INFINITY;
            #pragma unroll
            for (int d = 0; d < NDET; ++d) xmax = fmaxf(xmax, sx[base + d]);
            float sum = 0.0f;
            #pragma unroll
            for (int d = 0; d < NDET; ++d)
                sum += ss[base + d] * __expf(sx[base + d] - xmax) * w[d];
            out[sample] = __logf(fabsf(sum)) + xmax;
            out[n_samples + sample] = (sum > 0.0f) ? 1.0f : ((sum < 0.0f) ? -1.0f : 0.0f);
        }
    }
}

extern "C" void kernel_launch(void* const* d_in, const int* in_sizes, int n_in,
                              void* d_out, int out_size, void* d_ws, size_t ws_size,
                              hipStream_t stream)
{
    const float* a = (const float*)d_in[0];
    const float* b = (const float*)d_in[1];
    const float* w = (const float*)d_in[2];
    float* out = (float*)d_out;

    const int n_samples = in_sizes[0] / (NDET * NDIM * NDIM);
    const int blocks = (n_samples + 1) / 2;   // 2 samples (32 dets) per block
    logabssumdet_kernel<<<blocks, 128, 0, stream>>>(a, b, w, out, n_samples);
}

// Round 9
// 50.042 us; speedup vs baseline: 1.2735x; 1.2735x over previous
//
#include <hip/hip_runtime.h>
#include <math.h>

#define NDET 16
#define NDIM 16

// ---- quad (4-lane) DPP broadcast: pure VALU, no LDS path -----------------
template<int OWNER>
__device__ __forceinline__ float bcast4f(float v) {
    constexpr int ctrl = OWNER * 0x55;  // quad_perm:[OWNER]*4
    return __int_as_float(
        __builtin_amdgcn_mov_dpp(__float_as_int(v), ctrl, 0xF, 0xF, true));
}

// ---- Householder QR step (column K), 16x16 over a 4-lane quad ------------
// lane l owns columns 4l..4l+3 as c[j][row]; all indices compile-time.
// No pivot search, no row swap: unconditionally stable.
//   H_K x = -s*alpha*e1,  s = sign(x_K),  alpha = ||x||
//   v = x + s*alpha*e1,   beta = 2/(v'v) = 1/(alpha*|v_K|)
// prod accumulates alpha_K (>0); sgn accumulates s_K.
template<int K>
__device__ __forceinline__ void qr_step(float (&c)[4][16], float &prod, float &sgn) {
    constexpr int OWNER = K >> 2;   // lane owning global column K
    constexpr int KC    = K & 3;    // its local column index

    // two-chain sum of squares over active rows K..15 of own local column KC
    float s0 = 0.0f, s1 = 0.0f;
    #pragma unroll
    for (int i = K; i < 16; i += 2)     s0 = fmaf(c[KC][i], c[KC][i], s0);
    #pragma unroll
    for (int i = K + 1; i < 16; i += 2) s1 = fmaf(c[KC][i], c[KC][i], s1);

    const float n2    = bcast4f<OWNER>(s0 + s1);
    const float xK    = bcast4f<OWNER>(c[KC][K]);
    const float alpha = __builtin_amdgcn_sqrtf(n2);          // ||x|| > 0 a.s.
    const float vK    = xK + copysignf(alpha, xK);           // |vK| = alpha + |xK|
    const float beta  = __builtin_amdgcn_rcpf(alpha * fabsf(vK));
    prod *= alpha;
    sgn = (xK < 0.0f) ? -sgn : sgn;

    // broadcast the reflector v (rows K..15) to all lanes of the quad
    float bv[16];                       // const-indexed -> registers
    bv[K] = vK;
    #pragma unroll
    for (int i = K + 1; i < 16; ++i) bv[i] = bcast4f<OWNER>(c[KC][i]);

    // apply H to all 4 local columns (retired columns: active rows ~0 -> no-op)
    #pragma unroll
    for (int j = 0; j < 4; ++j) {
        float w0 = bv[K] * c[j][K], w1 = 0.0f;
        #pragma unroll
        for (int i = K + 1; i < 16; i += 2) w0 = fmaf(bv[i], c[j][i], w0);
        #pragma unroll
        for (int i = K + 2; i < 16; i += 2) w1 = fmaf(bv[i], c[j][i], w1);
        const float t = (w0 + w1) * beta;
        #pragma unroll
        for (int i = K; i < 16; ++i)
            c[j][i] = fmaf(-t, bv[i], c[j][i]);
    }
}

template<int K>
__device__ __forceinline__ void qr_all(float (&c)[4][16], float &prod, float &sgn) {
    qr_step<K>(c, prod, sgn);
    if constexpr (K < 14) qr_all<K + 1>(c, prod, sgn);
}

__global__ __launch_bounds__(256) void logabssumdet_kernel(
    const float* __restrict__ a,
    const float* __restrict__ b,
    const float* __restrict__ w,
    float* __restrict__ out,
    int n_samples)
{
    const int tid    = threadIdx.x;
    const int lane4  = tid & 3;
    const int group  = tid >> 2;                    // 0..63 in block
    const int mat_id = blockIdx.x * 64 + group;     // = sample*16 + det
    const int n_mats = n_samples * NDET;

    __shared__ float sx[64];
    __shared__ float ss[64];

    float x = 0.0f, sgn = 1.0f;

    if (mat_id < n_mats) {
        #pragma unroll 1   // one QR body in I-cache (rolled m-loop: R2-best)
        for (int m = 0; m < 2; ++m) {
            const float* src = (m == 0) ? a : b;
            const float4* mb =
                reinterpret_cast<const float4*>(src + (size_t)mat_id * (NDIM * NDIM)) + lane4;

            float c[4][16];
            #pragma unroll
            for (int i = 0; i < 16; ++i) {
                const float4 v = mb[i * 4];         // 64B contiguous per quad
                c[0][i] = v.x; c[1][i] = v.y; c[2][i] = v.z; c[3][i] = v.w;
            }

            float prod = 1.0f;                      // = prod of alpha_K (>0)
            qr_all<0>(c, prod, sgn);                // 15 reflections
            prod *= bcast4f<3>(c[3][15]);           // * R[15][15]

            // det = (prod of s_K, in sgn) * prod ; range-safe in f32:
            // alpha_K <= ||col|| ~ 8 -> prod in [~1e-8, ~4e13]
            x += __logf(fabsf(prod));
            sgn = (prod < 0.0f) ? -sgn : sgn;
        }
    }

    if (lane4 == 0) { sx[group] = x; ss[group] = sgn; }
    __syncthreads();

    // 4 samples per block; one thread finishes each sample's 16-det LSE
    if (tid < 4) {
        const int sample = blockIdx.x * 4 + tid;
        if (sample < n_samples) {
            const int base = tid * NDET;
            float xmax = -INFINITY;
            #pragma unroll
            for (int d = 0; d < NDET; ++d) xmax = fmaxf(xmax, sx[base + d]);
            float sum = 0.0f;
            #pragma unroll
            for (int d = 0; d < NDET; ++d)
                sum += ss[base + d] * __expf(sx[base + d] - xmax) * w[d];
            out[sample] = __logf(fabsf(sum)) + xmax;
            out[n_samples + sample] = (sum > 0.0f) ? 1.0f : ((sum < 0.0f) ? -1.0f : 0.0f);
        }
    }
}

extern "C" void kernel_launch(void* const* d_in, const int* in_sizes, int n_in,
                              void* d_out, int out_size, void* d_ws, size_t ws_size,
                              hipStream_t stream)
{
    const float* a = (const float*)d_in[0];
    const float* b = (const float*)d_in[1];
    const float* w = (const float*)d_in[2];
    float* out = (float*)d_out;

    const int n_samples = in_sizes[0] / (NDET * NDIM * NDIM);
    const int blocks = (n_samples + 3) / 4;   // 4 samples (64 dets) per block
    logabssumdet_kernel<<<blocks, 256, 0, stream>>>(a, b, w, out, n_samples);
}